// Round 5
// baseline (12639.284 us; speedup 1.0000x reference)
//
#include <hip/hip_runtime.h>

#define DEV static __device__ __forceinline__

typedef _Float16 half8  __attribute__((ext_vector_type(8)));
typedef _Float16 half4v __attribute__((ext_vector_type(4)));
typedef float    floatx4 __attribute__((ext_vector_type(4)));
typedef unsigned int u32;
typedef unsigned long long u64;
typedef u32 u32x4 __attribute__((ext_vector_type(4)));

// Split scale: lo = f16((v - f16(v)) * 1024); combine = hi + lo/1024.
#define SPLIT_S 1024.0f
#define SPLIT_R (1.0f / 1024.0f)

// async global->LDS, 16B/lane: LDS dest wave-uniform base + lane*16.
DEV void gl_lds16(const _Float16* g, _Float16* l) {
  __builtin_amdgcn_global_load_lds(
      (const __attribute__((address_space(1))) u32*)g,
      (__attribute__((address_space(3))) u32*)l, 16, 0, 0);
}

// LLC-coherent (bypass L1/L2) 16B load/store. Not atomic; 16B-aligned
// dwordx4 is single-transaction -> tag in the same 16B implies payload.
DEV u32x4 llc_load16(u64 addr) {
  u32x4 r;
  asm volatile("global_load_dwordx4 %0, %1, off sc0 sc1"
               : "=v"(r) : "v"(addr));
  return r;
}
DEV void llc_store16(u64 addr, u32x4 v) {
  asm volatile("global_store_dwordx4 %0, %1, off sc0 sc1"
               :: "v"(addr), "v"(v) : "memory");
}

// Overflow-safe fast tanh: tanh(x) = sign(x) * (1 - 2/(1+e^{2|x|})).
DEV float fast_tanh(float x) {
  const float e = __expf(2.0f * fabsf(x));
  return copysignf(1.0f - 2.0f / (1.0f + e), x);
}

// ---------------------------------------------------------------------------
// h_pub packet layout: 2 bufs x 8 rows x 128 g x {hi: 4 pkts, lo: 4 pkts} x 16B
//   addr(buf,r,g,part,lkp) = base + buf*131072 + (r*128+g)*128 + part*64 + lkp*16
//   packet = { payload: 4 halves of h[r][g*16+lkp*4 ..+4] (8B), tag, tag }
// h(tau) lives in buf[tau&1] with tag == tau.
// ---------------------------------------------------------------------------
// Convert W_out->f16; buf0 = packets of split(h0) tag 0; buf1 = tag-invalid.
__global__ __launch_bounds__(256) void k_convert(
    const float* __restrict__ wout, const float* __restrict__ h0,
    _Float16* __restrict__ WoutF, char* __restrict__ hpub)
{
  const int NW4 = (2048 * 2048) / 4;
  for (int i = blockIdx.x * 256 + threadIdx.x; i < NW4; i += gridDim.x * 256) {
    const float4 v = ((const float4*)wout)[i];
    half4v o;
    o[0] = (_Float16)v.x; o[1] = (_Float16)v.y;
    o[2] = (_Float16)v.z; o[3] = (_Float16)v.w;
    ((half4v*)WoutF)[i] = o;
  }
  for (int id = blockIdx.x * 256 + threadIdx.x; id < 8192; id += gridDim.x * 256) {
    const int r = id >> 10, g = (id >> 3) & 127, part = (id >> 2) & 1, lkp = id & 3;
    const floatx4 v = *(const floatx4*)(h0 + (size_t)r * 2048 + g * 16 + lkp * 4);
    union { _Float16 h[4]; u32 d[2]; } p;
#pragma unroll
    for (int j = 0; j < 4; ++j) {
      const _Float16 hi = (_Float16)v[j];
      p.h[j] = (part == 0) ? hi : (_Float16)((v[j] - (float)hi) * SPLIT_S);
    }
    const size_t slot = (size_t)(r * 128 + g) * 128 + part * 64 + lkp * 16;
    u32x4 pkt = { p.d[0], p.d[1], 0u, 0u };
    *(u32x4*)(hpub + slot) = pkt;
    u32x4 inv = { 0u, 0u, 0xFFFFFFFFu, 0xFFFFFFFFu };
    *(u32x4*)(hpub + 131072 + slot) = inv;
  }
}

// ---------------------------------------------------------------------------
// Split-f16 GEMM: C[m,n] = sum_k A[m,k]*B[n,k], A/B fp32 row-major (MxK, NxK).
// EPI 0: C = silu(v) fp32.  EPI 1: C[(t*8+b)*N+n] = v + bias[n] fp32.
template <int EPI>
__global__ __launch_bounds__(256) void k_gemm_split(
    const float* __restrict__ A, const float* __restrict__ B,
    float* __restrict__ C, const float* __restrict__ bias,
    int M, int N, int K)
{
  __shared__ _Float16 Ah[4096], Al[4096], Bh[4096], Bl[4096];
  const int tid  = threadIdx.x;
  const int lane = tid & 63, wave = tid >> 6;
  const int wm = wave >> 1, wn = wave & 1;
  const int tm = blockIdx.y * 128, tn = blockIdx.x * 128;
  const int lr = lane & 15, lk = lane >> 4;

  floatx4 acch[4][4] = {};
  floatx4 accl[4][4] = {};

  for (int k0 = 0; k0 < K; k0 += 32) {
    float4 av[4], bv[4];
#pragma unroll
    for (int q = 0; q < 4; ++q) {
      const int c = tid + q * 256;           // chunk 0..1023 (float4 units)
      const int rr = c >> 3, cc = (c & 7) * 4;
      av[q] = *(const float4*)(A + (size_t)(tm + rr) * K + k0 + cc);
      bv[q] = *(const float4*)(B + (size_t)(tn + rr) * K + k0 + cc);
    }
    __syncthreads();   // previous iteration's frag reads complete
#pragma unroll
    for (int q = 0; q < 4; ++q) {
      const int c = tid + q * 256;
      const int rr = c >> 3, cc = (c & 7) * 4;
      half4v ah, al, bh, bl;
#pragma unroll
      for (int j = 0; j < 4; ++j) {
        const float xa = av[q][j], xb = bv[q][j];
        const _Float16 ha = (_Float16)xa, hb = (_Float16)xb;
        ah[j] = ha; al[j] = (_Float16)((xa - (float)ha) * SPLIT_S);
        bh[j] = hb; bl[j] = (_Float16)((xb - (float)hb) * SPLIT_S);
      }
      *(half4v*)(Ah + rr * 32 + cc) = ah;
      *(half4v*)(Al + rr * 32 + cc) = al;
      *(half4v*)(Bh + rr * 32 + cc) = bh;
      *(half4v*)(Bl + rr * 32 + cc) = bl;
    }
    __syncthreads();

    half8 fah[4], fal[4], fbh[4], fbl[4];
#pragma unroll
    for (int mi = 0; mi < 4; ++mi) {
      const int off = (wm * 64 + mi * 16 + lr) * 32 + lk * 8;
      fah[mi] = *(const half8*)(Ah + off);
      fal[mi] = *(const half8*)(Al + off);
    }
#pragma unroll
    for (int ni = 0; ni < 4; ++ni) {
      const int off = (wn * 64 + ni * 16 + lr) * 32 + lk * 8;
      fbh[ni] = *(const half8*)(Bh + off);
      fbl[ni] = *(const half8*)(Bl + off);
    }
#pragma unroll
    for (int mi = 0; mi < 4; ++mi)
#pragma unroll
      for (int ni = 0; ni < 4; ++ni) {
        acch[mi][ni] = __builtin_amdgcn_mfma_f32_16x16x32_f16(fah[mi], fbh[ni], acch[mi][ni], 0, 0, 0);
        accl[mi][ni] = __builtin_amdgcn_mfma_f32_16x16x32_f16(
            fah[mi], fbl[ni],
            __builtin_amdgcn_mfma_f32_16x16x32_f16(fal[mi], fbh[ni], accl[mi][ni], 0, 0, 0),
            0, 0, 0);
      }
  }

#pragma unroll
  for (int mi = 0; mi < 4; ++mi)
#pragma unroll
    for (int ni = 0; ni < 4; ++ni) {
      const int gcol = tn + wn * 64 + ni * 16 + lr;
#pragma unroll
      for (int r = 0; r < 4; ++r) {
        const int grow = tm + wm * 64 + mi * 16 + lk * 4 + r;
        const float v = acch[mi][ni][r] + accl[mi][ni][r] * SPLIT_R;
        if (EPI == 0) {
          C[(size_t)grow * N + gcol] = v / (1.0f + __expf(-v));
        } else {
          const int tt = grow & 1023, bb = grow >> 10;
          C[(size_t)(tt * 8 + bb) * N + gcol] = v + bias[gcol];
        }
      }
    }
}

// ---------------------------------------------------------------------------
// Plain-f16 GEMM for y = (outs/8) . Wout^T, epilogue *8.
__global__ __launch_bounds__(256) void k_gemm_out(
    const _Float16* __restrict__ A, const _Float16* __restrict__ B,
    float* __restrict__ C, int M, int N, int K)
{
  __shared__ _Float16 As[4096];
  __shared__ _Float16 Bs[4096];
  const int tid  = threadIdx.x;
  const int lane = tid & 63, wave = tid >> 6;
  const int wm = wave >> 1, wn = wave & 1;
  const int tm = blockIdx.y * 128, tn = blockIdx.x * 128;
  const int lr = lane & 15, lk = lane >> 4;
  const int r0 = tid >> 2;
  const int c0 = (tid & 3) * 8;

  floatx4 acc[4][4] = {};

  for (int k0 = 0; k0 < K; k0 += 32) {
#pragma unroll
    for (int c = 0; c < 2; ++c) {
      const int row = c * 64 + r0;
      gl_lds16(A + (size_t)(tm + row) * K + k0 + c0, As + c * 2048 + wave * 512);
      gl_lds16(B + (size_t)(tn + row) * K + k0 + c0, Bs + c * 2048 + wave * 512);
    }
    __syncthreads();

    half8 af[4], bf[4];
#pragma unroll
    for (int mi = 0; mi < 4; ++mi)
      af[mi] = *(const half8*)(As + (wm * 64 + mi * 16 + lr) * 32 + lk * 8);
#pragma unroll
    for (int ni = 0; ni < 4; ++ni)
      bf[ni] = *(const half8*)(Bs + (wn * 64 + ni * 16 + lr) * 32 + lk * 8);
#pragma unroll
    for (int mi = 0; mi < 4; ++mi)
#pragma unroll
      for (int ni = 0; ni < 4; ++ni)
        acc[mi][ni] = __builtin_amdgcn_mfma_f32_16x16x32_f16(af[mi], bf[ni], acc[mi][ni], 0, 0, 0);
    __syncthreads();
  }

#pragma unroll
  for (int mi = 0; mi < 4; ++mi)
#pragma unroll
    for (int ni = 0; ni < 4; ++ni) {
      const int gcol = tn + wn * 64 + ni * 16 + lr;
#pragma unroll
      for (int r = 0; r < 4; ++r) {
        const int grow = tm + wm * 64 + mi * 16 + lk * 4 + r;
        C[(size_t)grow * N + gcol] = acc[mi][ni][r] * 8.0f;
      }
    }
}

// ---------------------------------------------------------------------------
// Persistent recurrence, split-f16, TAGGED-PACKET protocol (no flags, no acks).
// 128 WGs x 256 thr (1 WG/CU). Per step: spin-gather tagged h packets (retry
// only stale), MFMA, LDS reduce (parity dbuf, ONE barrier), wave0 tail:
// tanh + split + publish 2 tagged packets/owner (fire-and-forget) + outs.
__global__ __launch_bounds__(256, 1) void k_recur(
    const float* __restrict__ Wh, const float* __restrict__ wxp,
    const float* __restrict__ h0p, const float* __restrict__ lalpha,
    _Float16* __restrict__ outs, char* __restrict__ h_pub)
{
  __shared__ float red[2 * 256 * 4];
  const int tid = threadIdx.x;
  const int lane = tid & 63, wave = tid >> 6;
  const int g = blockIdx.x;
  const int e0 = g * 16;
  const int lr = lane & 15, lk = lane >> 4;
  const int lrc = lr & 7;   // lanes lr>=8 duplicate lr-8 (dead B cols)
  const float alpha = __expf(lalpha[0]);

  // Preload + split W_h fragments (fp32 global -> hi/lo f16 regs), once.
  half8 afh[16], afl[16];
#pragma unroll
  for (int ks = 0; ks < 16; ++ks) {
    const float* wp = Wh + (size_t)(e0 + lr) * 2048 + wave * 512 + ks * 32 + lk * 8;
    const float4 f0 = *(const float4*)wp;
    const float4 f1 = *(const float4*)(wp + 4);
    half8 h, l;
#pragma unroll
    for (int j = 0; j < 4; ++j) {
      const float a0 = ((const float*)&f0)[j], a1 = ((const float*)&f1)[j];
      const _Float16 h0_ = (_Float16)a0;
      const _Float16 h1_ = (_Float16)a1;
      h[j]     = h0_; l[j]     = (_Float16)((a0 - (float)h0_) * SPLIT_S);
      h[j + 4] = h1_; l[j + 4] = (_Float16)((a1 - (float)h1_) * SPLIT_S);
    }
    afh[ks] = h; afl[ks] = l;
  }

  const bool owner = (tid < 64) && (lr < 8);  // owns (batch lr, cols e0+lk*4..+4)
  float hr0 = 0.f, hr1 = 0.f, hr2 = 0.f, hr3 = 0.f;
  if (owner) {
    const float4 hv = *(const float4*)(h0p + (size_t)lr * 2048 + e0 + lk * 4);
    hr0 = hv.x; hr1 = hv.y; hr2 = hv.z; hr3 = hv.w;
  }

  const u64 hbase = (u64)h_pub;
  // Per-lane packet base: (row lrc, g-range of this wave's K-slice).
  const u64 cbase = (u64)((lrc * 128 + wave * 32 + (lk >> 1)) * 128 + (lk & 1) * 32);

  for (int t = 0; t < 1024; ++t) {
    // Prefetch wx_t (plain cached load, hidden under the gather).
    float4 wv = {0.f, 0.f, 0.f, 0.f};
    if (owner) wv = *(const float4*)(wxp + (size_t)(t * 8 + lr) * 2048 + e0 + lk * 4);

    const u64 gb = hbase + (u64)(t & 1) * 131072 + cbase;
    const u32 tag = (u32)t;
    u32x4 pk[32];
    half8 frh[16], frl[16];

#pragma unroll
    for (int part = 0; part < 2; ++part) {
      const u64 pb = gb + (u64)part * 64;
      // Issue all 32 packet loads in flight.
#pragma unroll
      for (int ks = 0; ks < 16; ++ks) {
        pk[2 * ks]     = llc_load16(pb + (u64)ks * 256);
        pk[2 * ks + 1] = llc_load16(pb + (u64)ks * 256 + 16);
      }
      asm volatile("s_waitcnt vmcnt(0)" ::: "memory");
      __builtin_amdgcn_sched_barrier(0);
      u32 m = 0;
#pragma unroll
      for (int i = 0; i < 32; ++i) m |= (pk[i][2] != tag) ? (1u << i) : 0u;
      while (m) {  // per-lane spin; re-issue only stale packets, all in flight
#pragma unroll
        for (int i = 0; i < 32; ++i)
          if (m & (1u << i))
            pk[i] = llc_load16(pb + (u64)(i >> 1) * 256 + (u64)(i & 1) * 16);
        asm volatile("s_waitcnt vmcnt(0)" ::: "memory");
        __builtin_amdgcn_sched_barrier(0);
#pragma unroll
        for (int i = 0; i < 32; ++i)
          if ((m & (1u << i)) && pk[i][2] == tag) m &= ~(1u << i);
      }
#pragma unroll
      for (int ks = 0; ks < 16; ++ks) {
        u32x4 f = { pk[2 * ks][0], pk[2 * ks][1], pk[2 * ks + 1][0], pk[2 * ks + 1][1] };
        if (part == 0) frh[ks] = __builtin_bit_cast(half8, f);
        else           frl[ks] = __builtin_bit_cast(half8, f);
      }
    }

    floatx4 ph[4] = {};
    floatx4 pl[4] = {};
#pragma unroll
    for (int ks = 0; ks < 16; ++ks) {
      ph[ks & 3] = __builtin_amdgcn_mfma_f32_16x16x32_f16(afh[ks], frh[ks], ph[ks & 3], 0, 0, 0);
      pl[ks & 3] = __builtin_amdgcn_mfma_f32_16x16x32_f16(
          afh[ks], frl[ks],
          __builtin_amdgcn_mfma_f32_16x16x32_f16(afl[ks], frh[ks], pl[ks & 3], 0, 0, 0),
          0, 0, 0);
    }
    const floatx4 pt = (ph[0] + ph[1] + ph[2] + ph[3]) +
                       (pl[0] + pl[1] + pl[2] + pl[3]) * SPLIT_R;
    *(floatx4*)&red[(((t & 1) * 256) + wave * 64 + lane) * 4] = pt;
    __syncthreads();   // the only barrier per step (red is parity-dbuf'd)

    if (tid < 64) {
      const floatx4* R = (const floatx4*)red + (t & 1) * 256;
      const floatx4 s = R[lane] + R[64 + lane] + R[128 + lane] + R[192 + lane];
      if (owner) {
        hr0 += alpha * fast_tanh(s[0] + wv.x);
        hr1 += alpha * fast_tanh(s[1] + wv.y);
        hr2 += alpha * fast_tanh(s[2] + wv.z);
        hr3 += alpha * fast_tanh(s[3] + wv.w);
        union { _Float16 h[4]; u32 d[2]; } hq, lq, ov;
        hq.h[0] = (_Float16)hr0; hq.h[1] = (_Float16)hr1;
        hq.h[2] = (_Float16)hr2; hq.h[3] = (_Float16)hr3;
        lq.h[0] = (_Float16)((hr0 - (float)hq.h[0]) * SPLIT_S);
        lq.h[1] = (_Float16)((hr1 - (float)hq.h[1]) * SPLIT_S);
        lq.h[2] = (_Float16)((hr2 - (float)hq.h[2]) * SPLIT_S);
        lq.h[3] = (_Float16)((hr3 - (float)hq.h[3]) * SPLIT_S);
        const u32 ntag = (u32)(t + 1);
        const u64 dst = hbase + (u64)((t + 1) & 1) * 131072 +
                        (u64)(lr * 128 + g) * 128 + (u64)lk * 16;
        u32x4 hpk = { hq.d[0], hq.d[1], ntag, ntag };
        u32x4 lpk = { lq.d[0], lq.d[1], ntag, ntag };
        llc_store16(dst,      hpk);   // fire-and-forget; consumers spin on tag
        llc_store16(dst + 64, lpk);
        // outs consumed only by the next dispatch -> off the critical path.
        ov.h[0] = (_Float16)((hr0 * hr0 / (1.f + __expf(-hr0))) * 0.125f);
        ov.h[1] = (_Float16)((hr1 * hr1 / (1.f + __expf(-hr1))) * 0.125f);
        ov.h[2] = (_Float16)((hr2 * hr2 / (1.f + __expf(-hr2))) * 0.125f);
        ov.h[3] = (_Float16)((hr3 * hr3 / (1.f + __expf(-hr3))) * 0.125f);
        *(u64*)(outs + (size_t)(lr * 1024 + t) * 2048 + e0 + lk * 4) = *(u64*)ov.h;
      }
    }
    // No further sync: h_pub overwrite safety and red-parity safety both
    // follow from "publish(t+1) happens only after full gather of h(t)".
  }
}

// ---------------------------------------------------------------------------
extern "C" void kernel_launch(void* const* d_in, const int* in_sizes, int n_in,
                              void* d_out, int out_size, void* d_ws, size_t ws_size,
                              hipStream_t stream)
{
  (void)in_sizes; (void)n_in; (void)out_size; (void)ws_size;
  const float* x    = (const float*)d_in[0];
  const float* h0   = (const float*)d_in[1];
  const float* Win  = (const float*)d_in[2];
  const float* Wx   = (const float*)d_in[3];
  const float* Wh   = (const float*)d_in[4];
  const float* bias = (const float*)d_in[5];
  const float* lal  = (const float*)d_in[6];
  const float* Wout = (const float*)d_in[7];

  char* ws = (char*)d_ws;
  float*    U     = (float*)(ws);                    // 67,108,864 B (fp32 u)
  _Float16* OUTS  = (_Float16*)(ws);                 // aliases U (U dead after GEMM2)
  _Float16* WoutF = (_Float16*)(ws + 67108864);      //  8,388,608 B
  char*     hpub  = ws + 75497472;                   //    262,144 B tagged packets
  float*    wxbuf = (float*)d_out;                   // wx staged in d_out

  const dim3 gg(16, 64);  // N/128, M/128

  k_convert<<<512, 256, 0, stream>>>(Wout, h0, WoutF, hpub);
  // u = silu(x . W_in^T)  (split-f16, fp32 out)
  k_gemm_split<0><<<gg, 256, 0, stream>>>(x, Win, U, nullptr, 8192, 2048, 2048);
  // wx[t][b][:] = u . W_x^T + b  (split-f16, fp32 out in d_out)
  k_gemm_split<1><<<gg, 256, 0, stream>>>(U, Wx, wxbuf, bias, 8192, 2048, 2048);
  // sequential scan; writes outs/8 (f16) over the dead U region
  k_recur<<<128, 256, 0, stream>>>(Wh, wxbuf, h0, lal, OUTS, hpub);
  // y = outs . W_out^T  (epilogue *8), overwrites d_out
  k_gemm_out<<<gg, 256, 0, stream>>>(OUTS, WoutF, (float*)d_out, 8192, 2048, 2048);
}

// Round 6
// 4629.466 us; speedup vs baseline: 2.7302x; 2.7302x over previous
//
#include <hip/hip_runtime.h>

#define DEV static __device__ __forceinline__

typedef _Float16 half8  __attribute__((ext_vector_type(8)));
typedef _Float16 half4v __attribute__((ext_vector_type(4)));
typedef float    floatx4 __attribute__((ext_vector_type(4)));
typedef unsigned int u32;
typedef unsigned long long u64;
typedef u32 u32x4 __attribute__((ext_vector_type(4)));

// Split scale: lo = f16((v - f16(v)) * 1024); combine = hi + lo/1024.
#define SPLIT_S 1024.0f
#define SPLIT_R (1.0f / 1024.0f)

// async global->LDS, 16B/lane: LDS dest wave-uniform base + lane*16.
DEV void gl_lds16(const _Float16* g, _Float16* l) {
  __builtin_amdgcn_global_load_lds(
      (const __attribute__((address_space(1))) u32*)g,
      (__attribute__((address_space(3))) u32*)l, 16, 0, 0);
}

// LLC-coherent (bypass L1/L2) 16B load / stores. Freshness via sc0+sc1.
DEV u32x4 llc_load16(u64 addr) {
  u32x4 r;
  asm volatile("global_load_dwordx4 %0, %1, off sc0 sc1"
               : "=v"(r) : "v"(addr));
  return r;
}
DEV void llc_store8(u64 addr, u64 v) {
  asm volatile("global_store_dwordx2 %0, %1, off sc0 sc1"
               :: "v"(addr), "v"(v) : "memory");
}
DEV void llc_store4(u64 addr, int v) {
  asm volatile("global_store_dword %0, %1, off sc0 sc1"
               :: "v"(addr), "v"(v) : "memory");
}

// Overflow-safe fast tanh: tanh(x) = sign(x) * (1 - 2/(1+e^{2|x|})).
DEV float fast_tanh(float x) {
  const float e = __expf(2.0f * fabsf(x));
  return copysignf(1.0f - 2.0f / (1.0f + e), x);
}

// ---------------------------------------------------------------------------
// h_pub layout (bytes): [parity(2) stride 65536][part(2) stride 32768]
//                       [b(8) stride 4096][k(2048) stride 2]   f16
// Convert W_out->f16; init h_pub parity0 = split(h0); zero flags.
__global__ __launch_bounds__(256) void k_convert(
    const float* __restrict__ wout, const float* __restrict__ h0,
    _Float16* __restrict__ WoutF, _Float16* __restrict__ hpub,
    int* __restrict__ flags)
{
  if (blockIdx.x == 0 && threadIdx.x < 128) flags[threadIdx.x] = 0;
  const int NW4 = (2048 * 2048) / 4;
  for (int i = blockIdx.x * 256 + threadIdx.x; i < NW4; i += gridDim.x * 256) {
    const float4 v = ((const float4*)wout)[i];
    half4v o;
    o[0] = (_Float16)v.x; o[1] = (_Float16)v.y;
    o[2] = (_Float16)v.z; o[3] = (_Float16)v.w;
    ((half4v*)WoutF)[i] = o;
  }
  for (int i = blockIdx.x * 256 + threadIdx.x; i < 8 * 2048; i += gridDim.x * 256) {
    const float v = h0[i];
    const _Float16 hi = (_Float16)v;
    hpub[i]          = hi;                                    // [p0][hi][b][k]
    hpub[16384 + i]  = (_Float16)((v - (float)hi) * SPLIT_S); // [p0][lo][b][k]
  }
}

// ---------------------------------------------------------------------------
// Split-f16 GEMM: C[m,n] = sum_k A[m,k]*B[n,k], A/B fp32 row-major (MxK, NxK).
// EPI 0: C = silu(v) fp32.  EPI 1: C[(t*8+b)*N+n] = v + bias[n] fp32.
template <int EPI>
__global__ __launch_bounds__(256) void k_gemm_split(
    const float* __restrict__ A, const float* __restrict__ B,
    float* __restrict__ C, const float* __restrict__ bias,
    int M, int N, int K)
{
  __shared__ _Float16 Ah[4096], Al[4096], Bh[4096], Bl[4096];
  const int tid  = threadIdx.x;
  const int lane = tid & 63, wave = tid >> 6;
  const int wm = wave >> 1, wn = wave & 1;
  const int tm = blockIdx.y * 128, tn = blockIdx.x * 128;
  const int lr = lane & 15, lk = lane >> 4;

  floatx4 acch[4][4] = {};
  floatx4 accl[4][4] = {};

  for (int k0 = 0; k0 < K; k0 += 32) {
    float4 av[4], bv[4];
#pragma unroll
    for (int q = 0; q < 4; ++q) {
      const int c = tid + q * 256;           // chunk 0..1023 (float4 units)
      const int rr = c >> 3, cc = (c & 7) * 4;
      av[q] = *(const float4*)(A + (size_t)(tm + rr) * K + k0 + cc);
      bv[q] = *(const float4*)(B + (size_t)(tn + rr) * K + k0 + cc);
    }
    __syncthreads();   // previous iteration's frag reads complete
#pragma unroll
    for (int q = 0; q < 4; ++q) {
      const int c = tid + q * 256;
      const int rr = c >> 3, cc = (c & 7) * 4;
      half4v ah, al, bh, bl;
#pragma unroll
      for (int j = 0; j < 4; ++j) {
        const float xa = av[q][j], xb = bv[q][j];
        const _Float16 ha = (_Float16)xa, hb = (_Float16)xb;
        ah[j] = ha; al[j] = (_Float16)((xa - (float)ha) * SPLIT_S);
        bh[j] = hb; bl[j] = (_Float16)((xb - (float)hb) * SPLIT_S);
      }
      *(half4v*)(Ah + rr * 32 + cc) = ah;
      *(half4v*)(Al + rr * 32 + cc) = al;
      *(half4v*)(Bh + rr * 32 + cc) = bh;
      *(half4v*)(Bl + rr * 32 + cc) = bl;
    }
    __syncthreads();

    half8 fah[4], fal[4], fbh[4], fbl[4];
#pragma unroll
    for (int mi = 0; mi < 4; ++mi) {
      const int off = (wm * 64 + mi * 16 + lr) * 32 + lk * 8;
      fah[mi] = *(const half8*)(Ah + off);
      fal[mi] = *(const half8*)(Al + off);
    }
#pragma unroll
    for (int ni = 0; ni < 4; ++ni) {
      const int off = (wn * 64 + ni * 16 + lr) * 32 + lk * 8;
      fbh[ni] = *(const half8*)(Bh + off);
      fbl[ni] = *(const half8*)(Bl + off);
    }
#pragma unroll
    for (int mi = 0; mi < 4; ++mi)
#pragma unroll
      for (int ni = 0; ni < 4; ++ni) {
        acch[mi][ni] = __builtin_amdgcn_mfma_f32_16x16x32_f16(fah[mi], fbh[ni], acch[mi][ni], 0, 0, 0);
        accl[mi][ni] = __builtin_amdgcn_mfma_f32_16x16x32_f16(
            fah[mi], fbl[ni],
            __builtin_amdgcn_mfma_f32_16x16x32_f16(fal[mi], fbh[ni], accl[mi][ni], 0, 0, 0),
            0, 0, 0);
      }
  }

#pragma unroll
  for (int mi = 0; mi < 4; ++mi)
#pragma unroll
    for (int ni = 0; ni < 4; ++ni) {
      const int gcol = tn + wn * 64 + ni * 16 + lr;
#pragma unroll
      for (int r = 0; r < 4; ++r) {
        const int grow = tm + wm * 64 + mi * 16 + lk * 4 + r;
        const float v = acch[mi][ni][r] + accl[mi][ni][r] * SPLIT_R;
        if (EPI == 0) {
          C[(size_t)grow * N + gcol] = v / (1.0f + __expf(-v));
        } else {
          const int tt = grow & 1023, bb = grow >> 10;
          C[(size_t)(tt * 8 + bb) * N + gcol] = v + bias[gcol];
        }
      }
    }
}

// ---------------------------------------------------------------------------
// Plain-f16 GEMM for y = (outs/8) . Wout^T, epilogue *8.
__global__ __launch_bounds__(256) void k_gemm_out(
    const _Float16* __restrict__ A, const _Float16* __restrict__ B,
    float* __restrict__ C, int M, int N, int K)
{
  __shared__ _Float16 As[4096];
  __shared__ _Float16 Bs[4096];
  const int tid  = threadIdx.x;
  const int lane = tid & 63, wave = tid >> 6;
  const int wm = wave >> 1, wn = wave & 1;
  const int tm = blockIdx.y * 128, tn = blockIdx.x * 128;
  const int lr = lane & 15, lk = lane >> 4;
  const int r0 = tid >> 2;
  const int c0 = (tid & 3) * 8;

  floatx4 acc[4][4] = {};

  for (int k0 = 0; k0 < K; k0 += 32) {
#pragma unroll
    for (int c = 0; c < 2; ++c) {
      const int row = c * 64 + r0;
      gl_lds16(A + (size_t)(tm + row) * K + k0 + c0, As + c * 2048 + wave * 512);
      gl_lds16(B + (size_t)(tn + row) * K + k0 + c0, Bs + c * 2048 + wave * 512);
    }
    __syncthreads();

    half8 af[4], bf[4];
#pragma unroll
    for (int mi = 0; mi < 4; ++mi)
      af[mi] = *(const half8*)(As + (wm * 64 + mi * 16 + lr) * 32 + lk * 8);
#pragma unroll
    for (int ni = 0; ni < 4; ++ni)
      bf[ni] = *(const half8*)(Bs + (wn * 64 + ni * 16 + lr) * 32 + lk * 8);
#pragma unroll
    for (int mi = 0; mi < 4; ++mi)
#pragma unroll
      for (int ni = 0; ni < 4; ++ni)
        acc[mi][ni] = __builtin_amdgcn_mfma_f32_16x16x32_f16(af[mi], bf[ni], acc[mi][ni], 0, 0, 0);
    __syncthreads();
  }

#pragma unroll
  for (int mi = 0; mi < 4; ++mi)
#pragma unroll
    for (int ni = 0; ni < 4; ++ni) {
      const int gcol = tn + wn * 64 + ni * 16 + lr;
#pragma unroll
      for (int r = 0; r < 4; ++r) {
        const int grow = tm + wm * 64 + mi * 16 + lk * 4 + r;
        C[(size_t)grow * N + gcol] = acc[mi][ni][r] * 8.0f;
      }
    }
}

// ---------------------------------------------------------------------------
// Persistent recurrence, split-f16. r4 flag protocol + COALESCED LDS GATHER.
// 128 WGs x 256 thr (1 WG/CU). Per step:
//   poll(wave0) -> barrier A
//   hi gather: 8x16B coalesced sc1 loads/thread -> vmcnt -> swizzled ds_write
//   barrier B1 -> issue lo gather (in flight) -> hi frags + 32 MFMA (Ah.Bh, Al.Bh)
//   vmcnt -> ds_write lo -> barrier B2 -> lo frags + 16 MFMA (Ah.Bl)
//   red write -> barrier C -> wave0 tail: reduce, tanh, publish, ack, flag, outs.
__global__ __launch_bounds__(256, 1) void k_recur(
    const float* __restrict__ Wh, const float* __restrict__ wxp,
    const float* __restrict__ h0p, const float* __restrict__ lalpha,
    _Float16* __restrict__ outs, _Float16* h_pub, int* flags)
{
  __shared__ u32x4 hs4[4096];      // 64KB: [part][8][2048] f16, XOR-swizzled
  __shared__ float red[256 * 4];   // 4KB
  char* const hs = (char*)hs4;
  const int tid = threadIdx.x;
  const int lane = tid & 63, wave = tid >> 6;
  const int g = blockIdx.x;
  const int e0 = g * 16;
  const int lr = lane & 15, lk = lane >> 4;
  const int lrc = lr & 7;   // lanes lr>=8 duplicate row lr-8 (dead B cols; LDS broadcast)
  const float alpha = __expf(lalpha[0]);

  // Preload + split W_h fragments (fp32 global -> hi/lo f16 regs), once.
  half8 afh[16], afl[16];
#pragma unroll
  for (int ks = 0; ks < 16; ++ks) {
    const float* wp = Wh + (size_t)(e0 + lr) * 2048 + wave * 512 + ks * 32 + lk * 8;
    const float4 f0 = *(const float4*)wp;
    const float4 f1 = *(const float4*)(wp + 4);
    half8 h, l;
#pragma unroll
    for (int j = 0; j < 4; ++j) {
      const float a0 = ((const float*)&f0)[j], a1 = ((const float*)&f1)[j];
      const _Float16 h0_ = (_Float16)a0;
      const _Float16 h1_ = (_Float16)a1;
      h[j]     = h0_; l[j]     = (_Float16)((a0 - (float)h0_) * SPLIT_S);
      h[j + 4] = h1_; l[j + 4] = (_Float16)((a1 - (float)h1_) * SPLIT_S);
    }
    afh[ks] = h; afl[ks] = l;
  }

  const bool owner = (tid < 64) && (lr < 8);  // owns (batch lr, cols e0+lk*4..+4)
  float hr0 = 0.f, hr1 = 0.f, hr2 = 0.f, hr3 = 0.f;
  if (owner) {
    const float4 hv = *(const float4*)(h0p + (size_t)lr * 2048 + e0 + lk * 4);
    hr0 = hv.x; hr1 = hv.y; hr2 = hv.z; hr3 = hv.w;
  }

  const u64 hbase = (u64)h_pub;
  const u64 flag_base = (u64)flags;
  // Per-lane LDS frag byte offset within a part (row lrc, this wave's K-slice).
  const int fb = (lrc * 4096 + (wave * 512 + lk * 8) * 2) ^ (lrc << 4);

  for (int t = 0; t < 1024; ++t) {
    // Prefetch wx_t (plain cached; consumed in tail, hidden under poll+gather).
    float4 wv = {0.f, 0.f, 0.f, 0.f};
    if (owner) wv = *(const float4*)(wxp + (size_t)(t * 8 + lr) * 2048 + e0 + lk * 4);

    // Poll: wave 0 only; lane watches flags[2*lane], flags[2*lane+1].
    if (t > 0 && wave == 0) {
      const u64* fp = (const u64*)flags + lane;
      for (;;) {
        const u64 fv = __hip_atomic_load(fp, __ATOMIC_RELAXED, __HIP_MEMORY_SCOPE_AGENT);
        if (__all(((int)fv >= t) && ((int)(fv >> 32) >= t))) break;
        __builtin_amdgcn_s_sleep(1);
      }
    }
    __syncthreads();   // A

    const u64 pbase = hbase + (u64)(t & 1) * 65536;

    // ---- hi gather: coalesced (consecutive lanes -> consecutive 16B) ----
    u32x4 gb[8];
#pragma unroll
    for (int i = 0; i < 8; ++i)
      gb[i] = llc_load16(pbase + (u64)tid * 16 + (u64)i * 4096);
    asm volatile("s_waitcnt vmcnt(0)" ::: "memory");
    __builtin_amdgcn_sched_barrier(0);
#pragma unroll
    for (int i = 0; i < 8; ++i)
      *(u32x4*)(hs + ((tid * 16 + i * 4096) ^ (i << 4))) = gb[i];
    __syncthreads();   // B1

    // ---- issue lo gather; stays in flight across the hi-MFMA phase ----
    u32x4 gl[8];
#pragma unroll
    for (int i = 0; i < 8; ++i)
      gl[i] = llc_load16(pbase + 32768 + (u64)tid * 16 + (u64)i * 4096);

    // ---- hi frags + MFMA: ph += Ah.Bh ; pl += Al.Bh ----
    floatx4 ph[4] = {};
    floatx4 pl[4] = {};
#pragma unroll
    for (int ks = 0; ks < 16; ++ks) {
      const half8 bh = *(const half8*)(hs + (fb ^ (ks * 64)));
      ph[ks & 3] = __builtin_amdgcn_mfma_f32_16x16x32_f16(afh[ks], bh, ph[ks & 3], 0, 0, 0);
      pl[ks & 3] = __builtin_amdgcn_mfma_f32_16x16x32_f16(afl[ks], bh, pl[ks & 3], 0, 0, 0);
    }

    asm volatile("s_waitcnt vmcnt(0)" ::: "memory");
    __builtin_amdgcn_sched_barrier(0);
#pragma unroll
    for (int i = 0; i < 8; ++i)
      *(u32x4*)(hs + 32768 + ((tid * 16 + i * 4096) ^ (i << 4))) = gl[i];
    __syncthreads();   // B2

    // ---- lo frags + MFMA: pl += Ah.Bl ----
#pragma unroll
    for (int ks = 0; ks < 16; ++ks) {
      const half8 bl = *(const half8*)(hs + 32768 + (fb ^ (ks * 64)));
      pl[ks & 3] = __builtin_amdgcn_mfma_f32_16x16x32_f16(afh[ks], bl, pl[ks & 3], 0, 0, 0);
    }
    const floatx4 pt = (ph[0] + ph[1] + ph[2] + ph[3]) +
                       (pl[0] + pl[1] + pl[2] + pl[3]) * SPLIT_R;
    *(floatx4*)&red[(wave * 64 + lane) * 4] = pt;
    __syncthreads();   // C

    if (tid < 64) {
      const floatx4* R = (const floatx4*)red;
      const floatx4 s = R[lane] + R[64 + lane] + R[128 + lane] + R[192 + lane];
      union { _Float16 h[4]; u64 u; } hv, lv, ov;
      if (owner) {
        hr0 += alpha * fast_tanh(s[0] + wv.x);
        hr1 += alpha * fast_tanh(s[1] + wv.y);
        hr2 += alpha * fast_tanh(s[2] + wv.z);
        hr3 += alpha * fast_tanh(s[3] + wv.w);
        hv.h[0] = (_Float16)hr0; hv.h[1] = (_Float16)hr1;
        hv.h[2] = (_Float16)hr2; hv.h[3] = (_Float16)hr3;
        lv.h[0] = (_Float16)((hr0 - (float)hv.h[0]) * SPLIT_S);
        lv.h[1] = (_Float16)((hr1 - (float)hv.h[1]) * SPLIT_S);
        lv.h[2] = (_Float16)((hr2 - (float)hv.h[2]) * SPLIT_S);
        lv.h[3] = (_Float16)((hr3 - (float)hv.h[3]) * SPLIT_S);
        const u64 dst = hbase + (u64)((t + 1) & 1) * 65536 +
                        (u64)lr * 4096 + (u64)(e0 + lk * 4) * 2;
        llc_store8(dst,         hv.u);   // [p'][hi][lr][cols]
        llc_store8(dst + 32768, lv.u);   // [p'][lo][lr][cols]
      }
      // Ack h stores at LLC, then publish the flag (single dword).
      asm volatile("s_waitcnt vmcnt(0)" ::: "memory");
      if (lane == 0) llc_store4(flag_base + (u64)g * 4, t + 1);
      if (owner) {
        // outs consumed only by the next dispatch -> off the critical path.
        ov.h[0] = (_Float16)((hr0 * hr0 / (1.f + __expf(-hr0))) * 0.125f);
        ov.h[1] = (_Float16)((hr1 * hr1 / (1.f + __expf(-hr1))) * 0.125f);
        ov.h[2] = (_Float16)((hr2 * hr2 / (1.f + __expf(-hr2))) * 0.125f);
        ov.h[3] = (_Float16)((hr3 * hr3 / (1.f + __expf(-hr3))) * 0.125f);
        *(u64*)(outs + (size_t)(lr * 1024 + t) * 2048 + e0 + lk * 4) = ov.u;
      }
    }
    // hs overwrite next step is safe: all frag reads complete before barrier C,
    // and the next ds_write happens only after barrier A (> C). red overwrite
    // is safe: wave0 finishes its red reads before reaching the next barrier A.
  }
}

// ---------------------------------------------------------------------------
extern "C" void kernel_launch(void* const* d_in, const int* in_sizes, int n_in,
                              void* d_out, int out_size, void* d_ws, size_t ws_size,
                              hipStream_t stream)
{
  (void)in_sizes; (void)n_in; (void)out_size; (void)ws_size;
  const float* x    = (const float*)d_in[0];
  const float* h0   = (const float*)d_in[1];
  const float* Win  = (const float*)d_in[2];
  const float* Wx   = (const float*)d_in[3];
  const float* Wh   = (const float*)d_in[4];
  const float* bias = (const float*)d_in[5];
  const float* lal  = (const float*)d_in[6];
  const float* Wout = (const float*)d_in[7];

  char* ws = (char*)d_ws;
  float*    U     = (float*)(ws);                    // 67,108,864 B (fp32 u)
  _Float16* OUTS  = (_Float16*)(ws);                 // aliases U (U dead after GEMM2)
  _Float16* WoutF = (_Float16*)(ws + 67108864);      //  8,388,608 B
  _Float16* hpub  = (_Float16*)(ws + 75497472);      //    131,072 B [2][2][8][2048] f16
  int*      flags = (int*)     (ws + 75628544);      //        512 B
  float*    wxbuf = (float*)d_out;                   // wx staged in d_out

  const dim3 gg(16, 64);  // N/128, M/128

  k_convert<<<512, 256, 0, stream>>>(Wout, h0, WoutF, hpub, flags);
  // u = silu(x . W_in^T)  (split-f16, fp32 out)
  k_gemm_split<0><<<gg, 256, 0, stream>>>(x, Win, U, nullptr, 8192, 2048, 2048);
  // wx[t][b][:] = u . W_x^T + b  (split-f16, fp32 out in d_out)
  k_gemm_split<1><<<gg, 256, 0, stream>>>(U, Wx, wxbuf, bias, 8192, 2048, 2048);
  // sequential scan; writes outs/8 (f16) over the dead U region
  k_recur<<<128, 256, 0, stream>>>(Wh, wxbuf, h0, lal, OUTS, hpub, flags);
  // y = outs . W_out^T  (epilogue *8), overwrites d_out
  k_gemm_out<<<gg, 256, 0, stream>>>(OUTS, WoutF, (float*)d_out, 8192, 2048, 2048);
}

// Round 7
// 4513.392 us; speedup vs baseline: 2.8004x; 1.0257x over previous
//
#include <hip/hip_runtime.h>

#define DEV static __device__ __forceinline__

typedef _Float16 half8  __attribute__((ext_vector_type(8)));
typedef _Float16 half4v __attribute__((ext_vector_type(4)));
typedef float    floatx4 __attribute__((ext_vector_type(4)));
typedef unsigned int u32;
typedef unsigned long long u64;
typedef u32 u32x4 __attribute__((ext_vector_type(4)));

// Split scale: lo = f16((v - f16(v)) * 1024); combine = hi + lo/1024.
#define SPLIT_S 1024.0f
#define SPLIT_R (1.0f / 1024.0f)

// async global->LDS, 16B/lane: LDS dest wave-uniform base + lane*16.
DEV void gl_lds16(const _Float16* g, _Float16* l) {
  __builtin_amdgcn_global_load_lds(
      (const __attribute__((address_space(1))) u32*)g,
      (__attribute__((address_space(3))) u32*)l, 16, 0, 0);
}

// LLC-coherent (bypass L1/L2) 16B load / stores. Freshness via sc0+sc1.
DEV u32x4 llc_load16(u64 addr) {
  u32x4 r;
  asm volatile("global_load_dwordx4 %0, %1, off sc0 sc1"
               : "=v"(r) : "v"(addr));
  return r;
}
DEV void llc_store8(u64 addr, u64 v) {
  asm volatile("global_store_dwordx2 %0, %1, off sc0 sc1"
               :: "v"(addr), "v"(v) : "memory");
}
DEV void llc_store4(u64 addr, int v) {
  asm volatile("global_store_dword %0, %1, off sc0 sc1"
               :: "v"(addr), "v"(v) : "memory");
}

// Overflow-safe fast tanh: tanh(x) = sign(x) * (1 - 2/(1+e^{2|x|})).
DEV float fast_tanh(float x) {
  const float e = __expf(2.0f * fabsf(x));
  return copysignf(1.0f - 2.0f / (1.0f + e), x);
}

// ---------------------------------------------------------------------------
// h_pub CHUNK-TRANSPOSED layout (bytes):
//   [parity(2) stride 65536][part(2) stride 32768][kchunk(256) stride 128][row(8) stride 16]
// 16B unit = h[row][kchunk*8 .. +8) as f16. This layout makes the consumer's
// MFMA B-fragment gather BOTH coalesced and shuffle-free (data lands in the
// exact lane that consumes it), eliminating all LDS staging.
// Convert W_out->f16; init h_pub parity0 = split(h0); zero flags.
__global__ __launch_bounds__(256) void k_convert(
    const float* __restrict__ wout, const float* __restrict__ h0,
    _Float16* __restrict__ WoutF, char* __restrict__ hpub,
    int* __restrict__ flags)
{
  if (blockIdx.x == 0 && threadIdx.x < 128) flags[threadIdx.x] = 0;
  const int NW4 = (2048 * 2048) / 4;
  for (int i = blockIdx.x * 256 + threadIdx.x; i < NW4; i += gridDim.x * 256) {
    const float4 v = ((const float4*)wout)[i];
    half4v o;
    o[0] = (_Float16)v.x; o[1] = (_Float16)v.y;
    o[2] = (_Float16)v.z; o[3] = (_Float16)v.w;
    ((half4v*)WoutF)[i] = o;
  }
  // 2048 cells: chunk c = id>>3 (256), row b = id&7.
  for (int id = blockIdx.x * 256 + threadIdx.x; id < 2048; id += gridDim.x * 256) {
    const int c = id >> 3, b = id & 7;
    union { _Float16 h[8]; u32x4 v; } hi, lo;
#pragma unroll
    for (int j = 0; j < 8; ++j) {
      const float v = h0[b * 2048 + c * 8 + j];
      const _Float16 h = (_Float16)v;
      hi.h[j] = h;
      lo.h[j] = (_Float16)((v - (float)h) * SPLIT_S);
    }
    *(u32x4*)(hpub + c * 128 + b * 16)         = hi.v;
    *(u32x4*)(hpub + 32768 + c * 128 + b * 16) = lo.v;
  }
}

// ---------------------------------------------------------------------------
// Split-f16 GEMM: C[m,n] = sum_k A[m,k]*B[n,k], A/B fp32 row-major (MxK, NxK).
// EPI 0: C = silu(v) fp32.  EPI 1: C[(t*8+b)*N+n] = v + bias[n] fp32.
template <int EPI>
__global__ __launch_bounds__(256) void k_gemm_split(
    const float* __restrict__ A, const float* __restrict__ B,
    float* __restrict__ C, const float* __restrict__ bias,
    int M, int N, int K)
{
  __shared__ _Float16 Ah[4096], Al[4096], Bh[4096], Bl[4096];
  const int tid  = threadIdx.x;
  const int lane = tid & 63, wave = tid >> 6;
  const int wm = wave >> 1, wn = wave & 1;
  const int tm = blockIdx.y * 128, tn = blockIdx.x * 128;
  const int lr = lane & 15, lk = lane >> 4;

  floatx4 acch[4][4] = {};
  floatx4 accl[4][4] = {};

  for (int k0 = 0; k0 < K; k0 += 32) {
    float4 av[4], bv[4];
#pragma unroll
    for (int q = 0; q < 4; ++q) {
      const int c = tid + q * 256;           // chunk 0..1023 (float4 units)
      const int rr = c >> 3, cc = (c & 7) * 4;
      av[q] = *(const float4*)(A + (size_t)(tm + rr) * K + k0 + cc);
      bv[q] = *(const float4*)(B + (size_t)(tn + rr) * K + k0 + cc);
    }
    __syncthreads();   // previous iteration's frag reads complete
#pragma unroll
    for (int q = 0; q < 4; ++q) {
      const int c = tid + q * 256;
      const int rr = c >> 3, cc = (c & 7) * 4;
      half4v ah, al, bh, bl;
#pragma unroll
      for (int j = 0; j < 4; ++j) {
        const float xa = av[q][j], xb = bv[q][j];
        const _Float16 ha = (_Float16)xa, hb = (_Float16)xb;
        ah[j] = ha; al[j] = (_Float16)((xa - (float)ha) * SPLIT_S);
        bh[j] = hb; bl[j] = (_Float16)((xb - (float)hb) * SPLIT_S);
      }
      *(half4v*)(Ah + rr * 32 + cc) = ah;
      *(half4v*)(Al + rr * 32 + cc) = al;
      *(half4v*)(Bh + rr * 32 + cc) = bh;
      *(half4v*)(Bl + rr * 32 + cc) = bl;
    }
    __syncthreads();

    half8 fah[4], fal[4], fbh[4], fbl[4];
#pragma unroll
    for (int mi = 0; mi < 4; ++mi) {
      const int off = (wm * 64 + mi * 16 + lr) * 32 + lk * 8;
      fah[mi] = *(const half8*)(Ah + off);
      fal[mi] = *(const half8*)(Al + off);
    }
#pragma unroll
    for (int ni = 0; ni < 4; ++ni) {
      const int off = (wn * 64 + ni * 16 + lr) * 32 + lk * 8;
      fbh[ni] = *(const half8*)(Bh + off);
      fbl[ni] = *(const half8*)(Bl + off);
    }
#pragma unroll
    for (int mi = 0; mi < 4; ++mi)
#pragma unroll
      for (int ni = 0; ni < 4; ++ni) {
        acch[mi][ni] = __builtin_amdgcn_mfma_f32_16x16x32_f16(fah[mi], fbh[ni], acch[mi][ni], 0, 0, 0);
        accl[mi][ni] = __builtin_amdgcn_mfma_f32_16x16x32_f16(
            fah[mi], fbl[ni],
            __builtin_amdgcn_mfma_f32_16x16x32_f16(fal[mi], fbh[ni], accl[mi][ni], 0, 0, 0),
            0, 0, 0);
      }
  }

#pragma unroll
  for (int mi = 0; mi < 4; ++mi)
#pragma unroll
    for (int ni = 0; ni < 4; ++ni) {
      const int gcol = tn + wn * 64 + ni * 16 + lr;
#pragma unroll
      for (int r = 0; r < 4; ++r) {
        const int grow = tm + wm * 64 + mi * 16 + lk * 4 + r;
        const float v = acch[mi][ni][r] + accl[mi][ni][r] * SPLIT_R;
        if (EPI == 0) {
          C[(size_t)grow * N + gcol] = v / (1.0f + __expf(-v));
        } else {
          const int tt = grow & 1023, bb = grow >> 10;
          C[(size_t)(tt * 8 + bb) * N + gcol] = v + bias[gcol];
        }
      }
    }
}

// ---------------------------------------------------------------------------
// Plain-f16 GEMM for y = (outs/8) . Wout^T, epilogue *8.
__global__ __launch_bounds__(256) void k_gemm_out(
    const _Float16* __restrict__ A, const _Float16* __restrict__ B,
    float* __restrict__ C, int M, int N, int K)
{
  __shared__ _Float16 As[4096];
  __shared__ _Float16 Bs[4096];
  const int tid  = threadIdx.x;
  const int lane = tid & 63, wave = tid >> 6;
  const int wm = wave >> 1, wn = wave & 1;
  const int tm = blockIdx.y * 128, tn = blockIdx.x * 128;
  const int lr = lane & 15, lk = lane >> 4;
  const int r0 = tid >> 2;
  const int c0 = (tid & 3) * 8;

  floatx4 acc[4][4] = {};

  for (int k0 = 0; k0 < K; k0 += 32) {
#pragma unroll
    for (int c = 0; c < 2; ++c) {
      const int row = c * 64 + r0;
      gl_lds16(A + (size_t)(tm + row) * K + k0 + c0, As + c * 2048 + wave * 512);
      gl_lds16(B + (size_t)(tn + row) * K + k0 + c0, Bs + c * 2048 + wave * 512);
    }
    __syncthreads();

    half8 af[4], bf[4];
#pragma unroll
    for (int mi = 0; mi < 4; ++mi)
      af[mi] = *(const half8*)(As + (wm * 64 + mi * 16 + lr) * 32 + lk * 8);
#pragma unroll
    for (int ni = 0; ni < 4; ++ni)
      bf[ni] = *(const half8*)(Bs + (wn * 64 + ni * 16 + lr) * 32 + lk * 8);
#pragma unroll
    for (int mi = 0; mi < 4; ++mi)
#pragma unroll
      for (int ni = 0; ni < 4; ++ni)
        acc[mi][ni] = __builtin_amdgcn_mfma_f32_16x16x32_f16(af[mi], bf[ni], acc[mi][ni], 0, 0, 0);
    __syncthreads();
  }

#pragma unroll
  for (int mi = 0; mi < 4; ++mi)
#pragma unroll
    for (int ni = 0; ni < 4; ++ni) {
      const int gcol = tn + wn * 64 + ni * 16 + lr;
#pragma unroll
      for (int r = 0; r < 4; ++r) {
        const int grow = tm + wm * 64 + mi * 16 + lk * 4 + r;
        C[(size_t)grow * N + gcol] = acc[mi][ni][r] * 8.0f;
      }
    }
}

// ---------------------------------------------------------------------------
// Persistent recurrence, split-f16, flag protocol + REGISTER-DIRECT gather.
// 128 WGs x 256 thr (1 WG/CU, 1 wave/SIMD -> 512 VGPR budget). Per step:
//   poll(wave0, 128 flags via u64/lane) -> barrier A
//   issue 16 hi + 16 lo chunk loads (coalesced AND frag-exact) -> vmcnt(16)
//   32 hi MFMAs (Ah.Bh, Al.Bh) -> vmcnt(0) -> 16 lo MFMAs (Ah.Bl)
//   red write -> barrier C -> wave0 tail: reduce, tanh, publish transposed
//   chunks, vmcnt ack, flag, outs.  NO LDS staging, NO swizzle, 2 barriers.
__global__ __launch_bounds__(256, 1) void k_recur(
    const float* __restrict__ Wh, const float* __restrict__ wxp,
    const float* __restrict__ h0p, const float* __restrict__ lalpha,
    _Float16* __restrict__ outs, char* __restrict__ h_pub, int* flags)
{
  __shared__ float red[256 * 4];   // 4KB (cross-wave reduce only)
  const int tid = threadIdx.x;
  const int lane = tid & 63, wave = tid >> 6;
  const int g = blockIdx.x;
  const int e0 = g * 16;
  const int lr = lane & 15, lk = lane >> 4;
  const int lrc = lr & 7;   // lanes lr>=8 duplicate row lr-8 (dead B cols; coalescer merges)
  const float alpha = __expf(lalpha[0]);

  // Preload + split W_h fragments (fp32 global -> hi/lo f16 regs), once.
  half8 afh[16], afl[16];
#pragma unroll
  for (int ks = 0; ks < 16; ++ks) {
    const float* wp = Wh + (size_t)(e0 + lr) * 2048 + wave * 512 + ks * 32 + lk * 8;
    const float4 f0 = *(const float4*)wp;
    const float4 f1 = *(const float4*)(wp + 4);
    half8 h, l;
#pragma unroll
    for (int j = 0; j < 4; ++j) {
      const float a0 = ((const float*)&f0)[j], a1 = ((const float*)&f1)[j];
      const _Float16 h0_ = (_Float16)a0;
      const _Float16 h1_ = (_Float16)a1;
      h[j]     = h0_; l[j]     = (_Float16)((a0 - (float)h0_) * SPLIT_S);
      h[j + 4] = h1_; l[j + 4] = (_Float16)((a1 - (float)h1_) * SPLIT_S);
    }
    afh[ks] = h; afl[ks] = l;
  }

  const bool owner = (tid < 64) && (lr < 8);  // owns (batch lr, cols e0+lk*4..+4)
  float hr0 = 0.f, hr1 = 0.f, hr2 = 0.f, hr3 = 0.f;
  if (owner) {
    const float4 hv = *(const float4*)(h0p + (size_t)lr * 2048 + e0 + lk * 4);
    hr0 = hv.x; hr1 = hv.y; hr2 = hv.z; hr3 = hv.w;
  }

  const u64 hbase = (u64)h_pub;
  const u64 flag_base = (u64)flags;
  // Per-lane gather base: chunk (wave*64 + ks*4 + lk), row lrc ->
  //   pb + (wave*64 + lk)*128 + lrc*16 + ks*512
  const u64 gb_off = (u64)((wave * 64 + lk) * 128 + lrc * 16);

  for (int t = 0; t < 1024; ++t) {
    // Prefetch wx_t (plain cached; consumed in tail, hidden under poll+gather).
    float4 wv = {0.f, 0.f, 0.f, 0.f};
    if (owner) wv = *(const float4*)(wxp + (size_t)(t * 8 + lr) * 2048 + e0 + lk * 4);

    // Poll: wave 0 only; lane watches flags[2*lane], flags[2*lane+1].
    if (t > 0 && wave == 0) {
      const u64* fp = (const u64*)flags + lane;
      for (;;) {
        const u64 fv = __hip_atomic_load(fp, __ATOMIC_RELAXED, __HIP_MEMORY_SCOPE_AGENT);
        if (__all(((int)fv >= t) && ((int)(fv >> 32) >= t))) break;
        __builtin_amdgcn_s_sleep(1);
      }
    }
    __syncthreads();   // A

    // ---- register-direct gather: hi then lo, all 32 loads in flight ----
    const u64 pb = hbase + (u64)(t & 1) * 65536 + gb_off;
    u32x4 sh[16], sl[16];
#pragma unroll
    for (int ks = 0; ks < 16; ++ks) sh[ks] = llc_load16(pb + (u64)ks * 512);
#pragma unroll
    for (int ks = 0; ks < 16; ++ks) sl[ks] = llc_load16(pb + 32768 + (u64)ks * 512);
    asm volatile("s_waitcnt vmcnt(16)" ::: "memory");   // hi complete
    __builtin_amdgcn_sched_barrier(0);

    // ---- hi MFMAs: ph += Ah.Bh ; pl += Al.Bh (lo loads still in flight) ----
    floatx4 ph[4] = {};
    floatx4 pl[4] = {};
#pragma unroll
    for (int ks = 0; ks < 16; ++ks) {
      const half8 bh = __builtin_bit_cast(half8, sh[ks]);
      ph[ks & 3] = __builtin_amdgcn_mfma_f32_16x16x32_f16(afh[ks], bh, ph[ks & 3], 0, 0, 0);
      pl[ks & 3] = __builtin_amdgcn_mfma_f32_16x16x32_f16(afl[ks], bh, pl[ks & 3], 0, 0, 0);
    }
    asm volatile("s_waitcnt vmcnt(0)" ::: "memory");    // lo complete
    __builtin_amdgcn_sched_barrier(0);

    // ---- lo MFMAs: pl += Ah.Bl ----
#pragma unroll
    for (int ks = 0; ks < 16; ++ks) {
      const half8 bl = __builtin_bit_cast(half8, sl[ks]);
      pl[ks & 3] = __builtin_amdgcn_mfma_f32_16x16x32_f16(afh[ks], bl, pl[ks & 3], 0, 0, 0);
    }
    const floatx4 pt = (ph[0] + ph[1] + ph[2] + ph[3]) +
                       (pl[0] + pl[1] + pl[2] + pl[3]) * SPLIT_R;
    *(floatx4*)&red[(wave * 64 + lane) * 4] = pt;
    __syncthreads();   // C

    if (tid < 64) {
      const floatx4* R = (const floatx4*)red;
      const floatx4 s = R[lane] + R[64 + lane] + R[128 + lane] + R[192 + lane];
      union { _Float16 h[4]; u64 u; } hv, lv, ov;
      if (owner) {
        hr0 += alpha * fast_tanh(s[0] + wv.x);
        hr1 += alpha * fast_tanh(s[1] + wv.y);
        hr2 += alpha * fast_tanh(s[2] + wv.z);
        hr3 += alpha * fast_tanh(s[3] + wv.w);
        hv.h[0] = (_Float16)hr0; hv.h[1] = (_Float16)hr1;
        hv.h[2] = (_Float16)hr2; hv.h[3] = (_Float16)hr3;
        lv.h[0] = (_Float16)((hr0 - (float)hv.h[0]) * SPLIT_S);
        lv.h[1] = (_Float16)((hr1 - (float)hv.h[1]) * SPLIT_S);
        lv.h[2] = (_Float16)((hr2 - (float)hv.h[2]) * SPLIT_S);
        lv.h[3] = (_Float16)((hr3 - (float)hv.h[3]) * SPLIT_S);
        // Transposed-chunk publish: chunk 2g+(lk>>1), row lr, half (lk&1).
        const u64 dst = hbase + (u64)((t + 1) & 1) * 65536 +
                        (u64)((2 * g + (lk >> 1)) * 128 + lr * 16 + (lk & 1) * 8);
        llc_store8(dst,         hv.u);   // hi
        llc_store8(dst + 32768, lv.u);   // lo
      }
      // Ack h stores at LLC, then publish the flag (single dword).
      asm volatile("s_waitcnt vmcnt(0)" ::: "memory");
      if (lane == 0) llc_store4(flag_base + (u64)g * 4, t + 1);
      if (owner) {
        // outs consumed only by the next dispatch -> off the critical path.
        ov.h[0] = (_Float16)((hr0 * hr0 / (1.f + __expf(-hr0))) * 0.125f);
        ov.h[1] = (_Float16)((hr1 * hr1 / (1.f + __expf(-hr1))) * 0.125f);
        ov.h[2] = (_Float16)((hr2 * hr2 / (1.f + __expf(-hr2))) * 0.125f);
        ov.h[3] = (_Float16)((hr3 * hr3 / (1.f + __expf(-hr3))) * 0.125f);
        *(u64*)(outs + (size_t)(lr * 1024 + t) * 2048 + e0 + lk * 4) = ov.u;
      }
    }
    // red overwrite for t+1 is safe: waves block at barrier A until wave0
    // (which finished its red reads) arrives there after the tail.
  }
}

// ---------------------------------------------------------------------------
extern "C" void kernel_launch(void* const* d_in, const int* in_sizes, int n_in,
                              void* d_out, int out_size, void* d_ws, size_t ws_size,
                              hipStream_t stream)
{
  (void)in_sizes; (void)n_in; (void)out_size; (void)ws_size;
  const float* x    = (const float*)d_in[0];
  const float* h0   = (const float*)d_in[1];
  const float* Win  = (const float*)d_in[2];
  const float* Wx   = (const float*)d_in[3];
  const float* Wh   = (const float*)d_in[4];
  const float* bias = (const float*)d_in[5];
  const float* lal  = (const float*)d_in[6];
  const float* Wout = (const float*)d_in[7];

  char* ws = (char*)d_ws;
  float*    U     = (float*)(ws);                    // 67,108,864 B (fp32 u)
  _Float16* OUTS  = (_Float16*)(ws);                 // aliases U (U dead after GEMM2)
  _Float16* WoutF = (_Float16*)(ws + 67108864);      //  8,388,608 B
  char*     hpub  = ws + 75497472;                   //    131,072 B chunk-transposed
  int*      flags = (int*)(ws + 75628544);           //        512 B
  float*    wxbuf = (float*)d_out;                   // wx staged in d_out

  const dim3 gg(16, 64);  // N/128, M/128

  k_convert<<<512, 256, 0, stream>>>(Wout, h0, WoutF, hpub, flags);
  // u = silu(x . W_in^T)  (split-f16, fp32 out)
  k_gemm_split<0><<<gg, 256, 0, stream>>>(x, Win, U, nullptr, 8192, 2048, 2048);
  // wx[t][b][:] = u . W_x^T + b  (split-f16, fp32 out in d_out)
  k_gemm_split<1><<<gg, 256, 0, stream>>>(U, Wx, wxbuf, bias, 8192, 2048, 2048);
  // sequential scan; writes outs/8 (f16) over the dead U region
  k_recur<<<128, 256, 0, stream>>>(Wh, wxbuf, h0, lal, OUTS, hpub, flags);
  // y = outs . W_out^T  (epilogue *8), overwrites d_out
  k_gemm_out<<<gg, 256, 0, stream>>>(OUTS, WoutF, (float*)d_out, 8192, 2048, 2048);
}